// Round 3
// baseline (288.731 us; speedup 1.0000x reference)
//
#include <hip/hip_runtime.h>

// GridGraph adjacency (COO) for all-active 2048x2048 rook grid.
// Output layout (float32): [vals(4N) | rows(4N) | cols(4N)], direction-major
// within each: d*N + p, d in ROOK order (down, up, right, left).
//
// R3: same as R2 but nontemporal store uses a native clang vector type
// (HIP float4 is a class — the builtin rejects it).

constexpr int HH = 2048;
constexpr int WW = 2048;
constexpr long long NN = (long long)HH * WW;

typedef float nfloat4 __attribute__((ext_vector_type(4)));

__device__ __forceinline__ void st4(float* p, float4 v) {
    nfloat4 nv = { v.x, v.y, v.z, v.w };
    __builtin_nontemporal_store(nv, (nfloat4*)p);
}

__global__ __launch_bounds__(256) void grid_adj_kernel(
    const float* __restrict__ w, float* __restrict__ out)
{
    const int t = blockIdx.x * blockDim.x + threadIdx.x;
    const int p = t << 3;                 // first of 8 consecutive elements
    const int i = p >> 11;                // p / W
    const int j = p & (WW - 1);           // p % W  (multiple of 8)

    float* __restrict__ vals = out;
    float* __restrict__ rows = out + 4 * NN;
    float* __restrict__ cols = out + 8 * NN;

    const float fp = (float)p;
    const float4 pf0 = make_float4(fp,       fp + 1.f, fp + 2.f, fp + 3.f);
    const float4 pf1 = make_float4(fp + 4.f, fp + 5.f, fp + 6.f, fp + 7.f);
    const float4 z4  = make_float4(0.f, 0.f, 0.f, 0.f);

    // center loads (used by left/right)
    const float4 c0 = *(const float4*)(w + p);
    const float4 c1 = *(const float4*)(w + p + 4);

    // d = 0: down (i+1, j) — wave-uniform validity per row
    {
        float4 v0 = z4, v1 = z4, r0 = z4, r1 = z4, cc0 = z4, cc1 = z4;
        if (i + 1 < HH) {
            v0 = *(const float4*)(w + p + WW);
            v1 = *(const float4*)(w + p + WW + 4);
            r0 = pf0; r1 = pf1;
            const float fq = fp + (float)WW;
            cc0 = make_float4(fq, fq + 1.f, fq + 2.f, fq + 3.f);
            cc1 = make_float4(fq + 4.f, fq + 5.f, fq + 6.f, fq + 7.f);
        }
        st4(vals + p, v0);      st4(vals + p + 4, v1);
        st4(rows + p, r0);      st4(rows + p + 4, r1);
        st4(cols + p, cc0);     st4(cols + p + 4, cc1);
    }

    // d = 1: up (i-1, j)
    {
        float4 v0 = z4, v1 = z4, r0 = z4, r1 = z4, cc0 = z4, cc1 = z4;
        if (i >= 1) {
            v0 = *(const float4*)(w + p - WW);
            v1 = *(const float4*)(w + p - WW + 4);
            r0 = pf0; r1 = pf1;
            const float fq = fp - (float)WW;
            cc0 = make_float4(fq, fq + 1.f, fq + 2.f, fq + 3.f);
            cc1 = make_float4(fq + 4.f, fq + 5.f, fq + 6.f, fq + 7.f);
        }
        const long long o = NN + p;
        st4(vals + o, v0);      st4(vals + o + 4, v1);
        st4(rows + o, r0);      st4(rows + o + 4, r1);
        st4(cols + o, cc0);     st4(cols + o + 4, cc1);
    }

    // d = 2: right (i, j+1) — only element k=7 at j==W-8 invalid
    {
        const bool lastok = (j < WW - 8);          // neighbor col j+8 exists
        float w8 = 0.f, r7 = 0.f, c7 = 0.f;
        if (lastok) {                              // also guards OOB read at p+8==N
            w8 = w[p + 8];
            r7 = fp + 7.f;
            c7 = fp + 8.f;
        }
        const long long o = 2 * NN + p;
        st4(vals + o,     make_float4(c0.y, c0.z, c0.w, c1.x));
        st4(vals + o + 4, make_float4(c1.y, c1.z, c1.w, w8));
        st4(rows + o,     pf0);
        st4(rows + o + 4, make_float4(pf1.x, pf1.y, pf1.z, r7));
        st4(cols + o,     make_float4(fp + 1.f, fp + 2.f, fp + 3.f, fp + 4.f));
        st4(cols + o + 4, make_float4(fp + 5.f, fp + 6.f, fp + 7.f, c7));
    }

    // d = 3: left (i, j-1) — only element k=0 at j==0 invalid
    {
        const bool firstok = (j > 0);
        float wm1 = 0.f, r0e = 0.f, c0e = 0.f;
        if (firstok) {                             // also guards OOB read at p==0
            wm1 = w[p - 1];
            r0e = fp;
            c0e = fp - 1.f;
        }
        const long long o = 3 * NN + p;
        st4(vals + o,     make_float4(wm1, c0.x, c0.y, c0.z));
        st4(vals + o + 4, make_float4(c0.w, c1.x, c1.y, c1.z));
        st4(rows + o,     make_float4(r0e, pf0.y, pf0.z, pf0.w));
        st4(rows + o + 4, pf1);
        st4(cols + o,     make_float4(c0e, fp, fp + 1.f, fp + 2.f));
        st4(cols + o + 4, make_float4(fp + 3.f, fp + 4.f, fp + 5.f, fp + 6.f));
    }
}

extern "C" void kernel_launch(void* const* d_in, const int* in_sizes, int n_in,
                              void* d_out, int out_size, void* d_ws, size_t ws_size,
                              hipStream_t stream) {
    // d_in[0] = activities (all-true bool, unused), d_in[1] = vertex_weights f32 [H*W]
    const float* w = (const float*)d_in[1];
    float* out = (float*)d_out;

    const int threads = 256;
    const int total_threads = (int)(NN / 8);       // 524,288 threads, 8 elems each
    const int blocks = total_threads / threads;    // 2048 blocks
    grid_adj_kernel<<<blocks, threads, 0, stream>>>(w, out);
}

// Round 4
// 219.976 us; speedup vs baseline: 1.3126x; 1.3126x over previous
//
#include <hip/hip_runtime.h>

// GridGraph adjacency (COO) for all-active 2048x2048 rook grid.
// Output layout (float32): [vals(4N) | rows(4N) | cols(4N)], direction-major
// within each: d*N + p, d in ROOK order (down, up, right, left).
//
// R4: back to 4 elems/thread (wave stores are fully contiguous 1 KiB — R3's
// 8/thread gave 32B-strided lanes per store = half-filled lines + NT = RMW).
// Keep NT stores (full lines now; output is write-once, keep it out of L2).
// Loads: 3 aligned float4 (center/up/down) + 2 guarded scalars; left/right
// weight vectors derived from the center load by register shift.

constexpr int HH = 2048;
constexpr int WW = 2048;
constexpr long long NN = (long long)HH * WW;

typedef float nfloat4 __attribute__((ext_vector_type(4)));

__device__ __forceinline__ void st4(float* p, float4 v) {
    nfloat4 nv = { v.x, v.y, v.z, v.w };
    __builtin_nontemporal_store(nv, (nfloat4*)p);
}

__global__ __launch_bounds__(256) void grid_adj_kernel(
    const float* __restrict__ w, float* __restrict__ out)
{
    const int t = blockIdx.x * blockDim.x + threadIdx.x;
    const int p = t << 2;                 // first of 4 consecutive elements
    const int i = p >> 11;                // p / W
    const int j = p & (WW - 1);           // p % W (multiple of 4)

    float* __restrict__ vals = out;
    float* __restrict__ rows = out + 4 * NN;
    float* __restrict__ cols = out + 8 * NN;

    const float fp = (float)p;
    const float4 pf = make_float4(fp, fp + 1.f, fp + 2.f, fp + 3.f);
    const float4 z4 = make_float4(0.f, 0.f, 0.f, 0.f);

    // center load — feeds left/right weight vectors
    const float4 c0 = *(const float4*)(w + p);

    // d = 0: down (i+1, j) — wave-uniform validity per row
    {
        float4 v = z4, r = z4, c = z4;
        if (i + 1 < HH) {
            v = *(const float4*)(w + p + WW);
            r = pf;
            const float fq = fp + (float)WW;
            c = make_float4(fq, fq + 1.f, fq + 2.f, fq + 3.f);
        }
        st4(vals + p, v);
        st4(rows + p, r);
        st4(cols + p, c);
    }

    // d = 1: up (i-1, j)
    {
        float4 v = z4, r = z4, c = z4;
        if (i >= 1) {
            v = *(const float4*)(w + p - WW);
            r = pf;
            const float fq = fp - (float)WW;
            c = make_float4(fq, fq + 1.f, fq + 2.f, fq + 3.f);
        }
        const long long o = NN + p;
        st4(vals + o, v);
        st4(rows + o, r);
        st4(cols + o, c);
    }

    // d = 2: right (i, j+1) — only k=3 at j==W-4 invalid
    {
        const bool lastok = (j < WW - 4);          // neighbor col j+4 exists
        float w4 = 0.f, r3 = 0.f, c3 = 0.f;
        if (lastok) {                              // also guards OOB read at p+4==N
            w4 = w[p + 4];
            r3 = fp + 3.f;
            c3 = fp + 4.f;
        }
        const long long o = 2 * NN + p;
        st4(vals + o, make_float4(c0.y, c0.z, c0.w, w4));
        st4(rows + o, make_float4(pf.x, pf.y, pf.z, r3));
        st4(cols + o, make_float4(fp + 1.f, fp + 2.f, fp + 3.f, c3));
    }

    // d = 3: left (i, j-1) — only k=0 at j==0 invalid
    {
        const bool firstok = (j > 0);
        float wm1 = 0.f, r0 = 0.f, c0e = 0.f;
        if (firstok) {                             // also guards OOB read at p==0
            wm1 = w[p - 1];
            r0 = fp;
            c0e = fp - 1.f;
        }
        const long long o = 3 * NN + p;
        st4(vals + o, make_float4(wm1, c0.x, c0.y, c0.z));
        st4(rows + o, make_float4(r0, pf.y, pf.z, pf.w));
        st4(cols + o, make_float4(c0e, fp, fp + 1.f, fp + 2.f));
    }
}

extern "C" void kernel_launch(void* const* d_in, const int* in_sizes, int n_in,
                              void* d_out, int out_size, void* d_ws, size_t ws_size,
                              hipStream_t stream) {
    // d_in[0] = activities (all-true bool, unused), d_in[1] = vertex_weights f32 [H*W]
    const float* w = (const float*)d_in[1];
    float* out = (float*)d_out;

    const int threads = 256;
    const int total_threads = (int)(NN / 4);       // 1,048,576 threads, 4 elems each
    const int blocks = total_threads / threads;    // 4096 blocks
    grid_adj_kernel<<<blocks, threads, 0, stream>>>(w, out);
}

// Round 5
// 213.252 us; speedup vs baseline: 1.3539x; 1.0315x over previous
//
#include <hip/hip_runtime.h>

// GridGraph adjacency (COO) for all-active 2048x2048 rook grid.
// Output layout (float32): [vals(4N) | rows(4N) | cols(4N)], direction-major
// within each: d*N + p, d in ROOK order (down, up, right, left).
//
// R5: R4 minus nontemporal stores (A/B showed NT cost ~6-10us on gfx950:
// R1 plain=213.8, R4 NT+fewer loads=220.0). Plain float4 stores, 4
// elems/thread (fully contiguous 1 KiB per wave store), 3 aligned float4
// loads + 2 guarded scalars per thread.

constexpr int HH = 2048;
constexpr int WW = 2048;
constexpr long long NN = (long long)HH * WW;

__global__ __launch_bounds__(256) void grid_adj_kernel(
    const float* __restrict__ w, float* __restrict__ out)
{
    const int t = blockIdx.x * blockDim.x + threadIdx.x;
    const int p = t << 2;                 // first of 4 consecutive elements
    const int i = p >> 11;                // p / W
    const int j = p & (WW - 1);           // p % W (multiple of 4)

    float* __restrict__ vals = out;
    float* __restrict__ rows = out + 4 * NN;
    float* __restrict__ cols = out + 8 * NN;

    const float fp = (float)p;
    const float4 pf = make_float4(fp, fp + 1.f, fp + 2.f, fp + 3.f);
    const float4 z4 = make_float4(0.f, 0.f, 0.f, 0.f);

    // center load — feeds left/right weight vectors
    const float4 c0 = *(const float4*)(w + p);

    // d = 0: down (i+1, j) — wave-uniform validity per row
    {
        float4 v = z4, r = z4, c = z4;
        if (i + 1 < HH) {
            v = *(const float4*)(w + p + WW);
            r = pf;
            const float fq = fp + (float)WW;
            c = make_float4(fq, fq + 1.f, fq + 2.f, fq + 3.f);
        }
        *(float4*)(vals + p) = v;
        *(float4*)(rows + p) = r;
        *(float4*)(cols + p) = c;
    }

    // d = 1: up (i-1, j)
    {
        float4 v = z4, r = z4, c = z4;
        if (i >= 1) {
            v = *(const float4*)(w + p - WW);
            r = pf;
            const float fq = fp - (float)WW;
            c = make_float4(fq, fq + 1.f, fq + 2.f, fq + 3.f);
        }
        const long long o = NN + p;
        *(float4*)(vals + o) = v;
        *(float4*)(rows + o) = r;
        *(float4*)(cols + o) = c;
    }

    // d = 2: right (i, j+1) — only k=3 at j==W-4 invalid
    {
        const bool lastok = (j < WW - 4);          // neighbor col j+4 exists
        float w4 = 0.f, r3 = 0.f, c3 = 0.f;
        if (lastok) {                              // also guards OOB read at p+4==N
            w4 = w[p + 4];
            r3 = fp + 3.f;
            c3 = fp + 4.f;
        }
        const long long o = 2 * NN + p;
        *(float4*)(vals + o) = make_float4(c0.y, c0.z, c0.w, w4);
        *(float4*)(rows + o) = make_float4(pf.x, pf.y, pf.z, r3);
        *(float4*)(cols + o) = make_float4(fp + 1.f, fp + 2.f, fp + 3.f, c3);
    }

    // d = 3: left (i, j-1) — only k=0 at j==0 invalid
    {
        const bool firstok = (j > 0);
        float wm1 = 0.f, r0 = 0.f, c0e = 0.f;
        if (firstok) {                             // also guards OOB read at p==0
            wm1 = w[p - 1];
            r0 = fp;
            c0e = fp - 1.f;
        }
        const long long o = 3 * NN + p;
        *(float4*)(vals + o) = make_float4(wm1, c0.x, c0.y, c0.z);
        *(float4*)(rows + o) = make_float4(r0, pf.y, pf.z, pf.w);
        *(float4*)(cols + o) = make_float4(c0e, fp, fp + 1.f, fp + 2.f);
    }
}

extern "C" void kernel_launch(void* const* d_in, const int* in_sizes, int n_in,
                              void* d_out, int out_size, void* d_ws, size_t ws_size,
                              hipStream_t stream) {
    // d_in[0] = activities (all-true bool, unused), d_in[1] = vertex_weights f32 [H*W]
    const float* w = (const float*)d_in[1];
    float* out = (float*)d_out;

    const int threads = 256;
    const int total_threads = (int)(NN / 4);       // 1,048,576 threads, 4 elems each
    const int blocks = total_threads / threads;    // 4096 blocks
    grid_adj_kernel<<<blocks, threads, 0, stream>>>(w, out);
}